// Round 1
// baseline (1822.329 us; speedup 1.0000x reference)
//
#include <hip/hip_runtime.h>

// Shapes (fixed by the reference)
#define Bb 4
#define Hh 16
#define Ss 2048
#define Dd 128

typedef __bf16 bf16x8 __attribute__((ext_vector_type(8)));
typedef __bf16 bf16x4 __attribute__((ext_vector_type(4)));
typedef float f32x4 __attribute__((ext_vector_type(4)));

// ---------- prep: fp32 -> bf16 flat for Q and K ----------
__global__ void k_cvt(const float4* __restrict__ Q, const float4* __restrict__ K,
                      bf16x4* __restrict__ Qb, bf16x4* __restrict__ Kb) {
    size_t i = (size_t)blockIdx.x * 256 + threadIdx.x;
    float4 q = Q[i], k = K[i];
    Qb[i] = (bf16x4){(__bf16)q.x, (__bf16)q.y, (__bf16)q.z, (__bf16)q.w};
    Kb[i] = (bf16x4){(__bf16)k.x, (__bf16)k.y, (__bf16)k.z, (__bf16)k.w};
}

// ---------- prep: V fp32 [bh][k][d] -> bf16 V^T [bh][d][k] ----------
__global__ void k_vt(const float* __restrict__ V, __bf16* __restrict__ VT) {
    __shared__ __bf16 lds[64][65];
    int k0 = blockIdx.x * 64, d0 = blockIdx.y * 64, bh = blockIdx.z;
    int t = threadIdx.x;
    for (int i = 0; i < 16; ++i) {
        int idx = i * 256 + t;
        int kl = idx >> 6, dl = idx & 63;
        lds[kl][dl] = (__bf16)V[((size_t)(bh * Ss + k0 + kl)) * Dd + d0 + dl];
    }
    __syncthreads();
    for (int i = 0; i < 16; ++i) {
        int idx = i * 256 + t;
        int dl = idx >> 6, kl = idx & 63;
        VT[((size_t)(bh * Dd + d0 + dl)) * Ss + k0 + kl] = lds[kl][dl];
    }
}

// ---------- prep: mask fp32 [b][q][k] -> bits maskT[b][k][q/32] (bit=1 => masked) ----------
__global__ void k_mask(const float* __restrict__ M, unsigned* __restrict__ maskT) {
    __shared__ unsigned char lds[64][68];
    int k0 = blockIdx.x * 64, q0 = blockIdx.y * 64, b = blockIdx.z;
    int t = threadIdx.x;
    for (int i = 0; i < 16; ++i) {
        int idx = i * 256 + t;
        int ql = idx >> 6, kl = idx & 63;
        lds[ql][kl] = (M[((size_t)(b * Ss + q0 + ql)) * Ss + k0 + kl] != 0.0f) ? 1 : 0;
    }
    __syncthreads();
    if (t < 128) {
        int kl = t >> 1, wsel = t & 1;
        unsigned wv = 0;
        for (int j = 0; j < 32; ++j)
            wv |= ((unsigned)lds[wsel * 32 + j][kl]) << j;
        maskT[((size_t)(b * Ss + k0 + kl)) * (Ss / 32) + (q0 >> 5) + wsel] = wv;
    }
}

// ---------- main fused attention ----------
// grid (S/64, B*H), block 256 (4 waves). Each block: 64 q-rows, full K sweep x2.
__global__ __launch_bounds__(256, 2) void attn_kernel(
    const __bf16* __restrict__ Qb, const __bf16* __restrict__ Kb,
    const __bf16* __restrict__ VTb, const unsigned* __restrict__ maskT,
    float* __restrict__ out, float* __restrict__ attn) {
    __shared__ __align__(16) __bf16 Qs[64][136];   // +8 pad -> 2-way max bank aliasing
    __shared__ __align__(16) __bf16 Ks[64][136];
    __shared__ __align__(16) __bf16 VTs[128][72];  // [d][k], +8 pad
    __shared__ __align__(16) __bf16 Ps[4][16][72]; // per-wave P tile (C->A layout bridge)
    __shared__ float linv[64];

    const int t = threadIdx.x;
    const int w = t >> 6, lane = t & 63, quad = lane >> 4, l16 = lane & 15;
    const int bh = blockIdx.y, b = bh >> 4;
    const int q0 = blockIdx.x << 6;

    // stage Q tile (once)
    {
        const int row = t >> 4, col = (t & 15) << 3;
        for (int p = 0; p < 4; ++p) {
            int r = p * 16 + row;
            float4 v = *(const float4*)(Qb + ((size_t)(bh * Ss + q0 + r)) * Dd + col);
            *(float4*)&Qs[r][col] = v;
        }
    }
    const int qw = (q0 >> 5) + (w >> 1);             // mask word index for this wave
    const int bitbase = ((w & 1) << 4) + (quad << 2); // + r = bit for row quad*4+r

    __syncthreads();
    bf16x8 aq[4];
    for (int kd = 0; kd < 4; ++kd)
        aq[kd] = *(const bf16x8*)&Qs[w * 16 + l16][kd * 32 + quad * 8];

    float rsum[4] = {0.f, 0.f, 0.f, 0.f};

    // ---- phase 1: row sums of exp(scores) ----
    for (int k0 = 0; k0 < Ss; k0 += 64) {
        __syncthreads();
        {
            const int row = t >> 4, col = (t & 15) << 3;
            for (int p = 0; p < 4; ++p) {
                int r = p * 16 + row;
                float4 v = *(const float4*)(Kb + ((size_t)(bh * Ss + k0 + r)) * Dd + col);
                *(float4*)&Ks[r][col] = v;
            }
        }
        __syncthreads();
        for (int nt = 0; nt < 4; ++nt) {
            f32x4 acc = {0.f, 0.f, 0.f, 0.f};
            for (int kd = 0; kd < 4; ++kd) {
                bf16x8 bk = *(const bf16x8*)&Ks[nt * 16 + l16][kd * 32 + quad * 8];
                acc = __builtin_amdgcn_mfma_f32_16x16x32_bf16(aq[kd], bk, acc, 0, 0, 0);
            }
            int col = k0 + nt * 16 + l16;
            unsigned mw = maskT[((size_t)(b * Ss + col)) * (Ss / 32) + qw];
            for (int r = 0; r < 4; ++r) {
                float p = ((mw >> (bitbase + r)) & 1u) ? 0.0f
                                                       : __expf(acc[r] * 0.0078125f);
                rsum[r] += p;
            }
        }
    }
    // reduce across the 16 lanes of each quad (cols) -> full row sums
    for (int r = 0; r < 4; ++r) {
        float v = rsum[r];
        v += __shfl_xor(v, 1, 16);
        v += __shfl_xor(v, 2, 16);
        v += __shfl_xor(v, 4, 16);
        v += __shfl_xor(v, 8, 16);
        rsum[r] = v;
    }
    if (l16 == 0)
        for (int r = 0; r < 4; ++r)
            linv[w * 16 + quad * 4 + r] = 1.0f / rsum[r];
    __syncthreads();
    float li[4];
    for (int r = 0; r < 4; ++r) li[r] = linv[w * 16 + quad * 4 + r];

    f32x4 oacc[8];
    for (int d = 0; d < 8; ++d) oacc[d] = (f32x4){0.f, 0.f, 0.f, 0.f};

    // ---- phase 2: attn write + PV ----
    for (int k0 = 0; k0 < Ss; k0 += 64) {
        __syncthreads();
        {
            const int row = t >> 4, col = (t & 15) << 3;
            for (int p = 0; p < 4; ++p) {
                int r = p * 16 + row;
                float4 v = *(const float4*)(Kb + ((size_t)(bh * Ss + k0 + r)) * Dd + col);
                *(float4*)&Ks[r][col] = v;
            }
            const int vrow = t >> 3, vcol = (t & 7) << 3;
            for (int p = 0; p < 4; ++p) {
                int r = p * 32 + vrow;
                float4 v = *(const float4*)(VTb + ((size_t)(bh * Dd + r)) * Ss + k0 + vcol);
                *(float4*)&VTs[r][vcol] = v;
            }
        }
        __syncthreads();
        for (int nt = 0; nt < 4; ++nt) {
            f32x4 acc = {0.f, 0.f, 0.f, 0.f};
            for (int kd = 0; kd < 4; ++kd) {
                bf16x8 bk = *(const bf16x8*)&Ks[nt * 16 + l16][kd * 32 + quad * 8];
                acc = __builtin_amdgcn_mfma_f32_16x16x32_bf16(aq[kd], bk, acc, 0, 0, 0);
            }
            int col = k0 + nt * 16 + l16;
            unsigned mw = maskT[((size_t)(b * Ss + col)) * (Ss / 32) + qw];
            for (int r = 0; r < 4; ++r) {
                float p = ((mw >> (bitbase + r)) & 1u)
                              ? 0.0f
                              : __expf(acc[r] * 0.0078125f) * li[r];
                attn[((size_t)(bh * Ss + q0 + w * 16 + quad * 4 + r)) * Ss + col] = p;
                Ps[w][quad * 4 + r][nt * 16 + l16] = (__bf16)p;
            }
        }
        // PV: wave-private LDS round-trip (per-wave in-order DS pipe; no barrier needed)
        for (int kg = 0; kg < 2; ++kg) {
            bf16x8 ap = *(const bf16x8*)&Ps[w][l16][kg * 32 + quad * 8];
            for (int dg = 0; dg < 8; ++dg) {
                bf16x8 bv = *(const bf16x8*)&VTs[dg * 16 + l16][kg * 32 + quad * 8];
                oacc[dg] = __builtin_amdgcn_mfma_f32_16x16x32_bf16(ap, bv, oacc[dg], 0, 0, 0);
            }
        }
    }
    // epilogue
    for (int dg = 0; dg < 8; ++dg)
        for (int r = 0; r < 4; ++r)
            out[((size_t)(bh * Ss + q0 + w * 16 + quad * 4 + r)) * Dd + dg * 16 + l16] =
                oacc[dg][r];
}

extern "C" void kernel_launch(void* const* d_in, const int* in_sizes, int n_in,
                              void* d_out, int out_size, void* d_ws, size_t ws_size,
                              hipStream_t stream) {
    const float* Q = (const float*)d_in[0];
    const float* K = (const float*)d_in[1];
    const float* V = (const float*)d_in[2];
    const float* M = (const float*)d_in[3];

    float* out = (float*)d_out;                       // B*H*S*D = 16,777,216 floats
    float* attn = out + (size_t)Bb * Hh * Ss * Dd;    // then B*H*S*S

    // workspace layout (needs ~98 MB)
    char* ws = (char*)d_ws;
    __bf16* Qb = (__bf16*)ws;                          // 33,554,432 B
    __bf16* Kb = (__bf16*)(ws + 33554432);             // 33,554,432 B
    __bf16* VTb = (__bf16*)(ws + 67108864);            // 33,554,432 B
    unsigned* maskT = (unsigned*)(ws + 100663296);     // 2,097,152 B

    k_cvt<<<16384, 256, 0, stream>>>((const float4*)Q, (const float4*)K,
                                     (bf16x4*)Qb, (bf16x4*)Kb);
    k_vt<<<dim3(32, 2, 64), 256, 0, stream>>>(V, VTb);
    k_mask<<<dim3(32, 32, 4), 256, 0, stream>>>(M, maskT);
    attn_kernel<<<dim3(32, 64), 256, 0, stream>>>(Qb, Kb, VTb, maskT, out, attn);
}